// Round 3
// baseline (207.848 us; speedup 1.0000x reference)
//
#include <hip/hip_runtime.h>

typedef float f4 __attribute__((ext_vector_type(4)));

#define Hdim 64
#define Wdim 64
#define Cdim 256
#define HW (Hdim * Wdim)

// Block = (b, h, w-half). 512 blocks x 512 threads.
// XCD pinning: xcd = blockIdx.x & 7 owns one (batch, h-half) pair ->
// working set 38 rows x 256 ch x 64 w x 4B = 2.5 MB < 4 MB per-XCD L2.
__global__ __launch_bounds__(512) void selfattn_kernel(const float* __restrict__ x,
                                                       float* __restrict__ out)
{
    const int bid = blockIdx.x;
    const int xcd = bid & 7;
    const int seq = bid >> 3;          // 0..63
    const int b   = xcd >> 1;          // 2 XCDs per batch
    const int hh  = xcd & 1;           // h-half owned by this XCD
    const int h   = hh * 32 + (seq >> 1);
    const int wh  = seq & 1;           // w-half
    const int wbase = wh * 32;
    const int t = threadIdx.x;

    __shared__ float cenBuf[256][32];  // center row, all channels, this w-half (32 KB)
    __shared__ float simRed[49][32];
    __shared__ float attnBuf[49][32];
    __shared__ float redBuf[7][32];
    __shared__ float psumBuf[7][32];

    const float* xb = x + (size_t)b * (Cdim * HW);

    // ---------------- Stage center row into LDS ----------------
    {
        const float* cen = xb + h * Wdim + wbase;
        #pragma unroll
        for (int p = 0; p < 4; ++p) {
            int fidx = p * 512 + t;       // 2048 f4 total
            int c = fidx >> 3;
            int q = fidx & 7;
            f4 v = *(const f4*)(cen + (size_t)c * HW + q * 4);
            *(f4*)&cenBuf[c][q * 4] = v;
        }
    }
    __syncthreads();

    // ---------------- Phase A: sim[k][w] ----------------
    // thread = (w4: lane bits 0..2, cp: lane bits 3..5, dy: wave id)
    // channel for iter i: c = i*8 + cp. window f[j] <-> position w0g-4+j.
    {
        const int w4 = t & 7;
        const int cp = (t >> 3) & 7;
        const int dy = t >> 6;            // 0..7; dy==7 idle
        const int lw0 = w4 * 4;
        const int w0g = wbase + lw0;

        float sim[7][4];
        #pragma unroll
        for (int dx = 0; dx < 7; ++dx)
            #pragma unroll
            for (int p = 0; p < 4; ++p) sim[dx][p] = 0.f;

        if (dy < 7) {
            const int row = h + dy - 3;
            if (row >= 0 && row < Hdim) {
                const bool hasL = (w0g != 0);
                const bool hasR = (w0g != 60);
                const float* xr = xb + (size_t)cp * HW + row * Wdim;

#define LOADWIN_A(F, C, I)                                                          \
                {                                                                   \
                    const float* xp = xr + (size_t)(I) * (8 * HW);                  \
                    if (hasL) { f4 v = *(const f4*)(xp + w0g - 4);                  \
                        F[0]=v.x; F[1]=v.y; F[2]=v.z; F[3]=v.w; }                   \
                    else { F[0]=0.f; F[1]=0.f; F[2]=0.f; F[3]=0.f; }                \
                    { f4 v = *(const f4*)(xp + w0g);                                \
                        F[4]=v.x; F[5]=v.y; F[6]=v.z; F[7]=v.w; }                   \
                    if (hasR) { f4 v = *(const f4*)(xp + w0g + 4);                  \
                        F[8]=v.x; F[9]=v.y; F[10]=v.z; F[11]=v.w; }                 \
                    else { F[8]=0.f; F[9]=0.f; F[10]=0.f; F[11]=0.f; }              \
                    C = *(const f4*)&cenBuf[(I) * 8 + cp][lw0];                     \
                }

#define COMPUTE_A(F, C)                                                             \
                _Pragma("unroll")                                                   \
                for (int dx = 0; dx < 7; ++dx)                                      \
                    _Pragma("unroll")                                               \
                    for (int p = 0; p < 4; ++p)                                     \
                        sim[dx][p] += C[p] * F[dx + p + 1];

                float bufA[12], bufB[12];
                f4 cenA, cenB;
                LOADWIN_A(bufA, cenA, 0);
                for (int i = 0; i < 30; i += 2) {
                    LOADWIN_A(bufB, cenB, i + 1);
                    COMPUTE_A(bufA, cenA);
                    LOADWIN_A(bufA, cenA, i + 2);
                    COMPUTE_A(bufB, cenB);
                }
                LOADWIN_A(bufB, cenB, 31);
                COMPUTE_A(bufA, cenA);
                COMPUTE_A(bufB, cenB);
#undef LOADWIN_A
#undef COMPUTE_A
            }
            // reduce over 8 channel partitions (lane bits 3..5)
            #pragma unroll
            for (int dx = 0; dx < 7; ++dx)
                #pragma unroll
                for (int p = 0; p < 4; ++p) {
                    float v = sim[dx][p];
                    v += __shfl_xor(v, 8);
                    v += __shfl_xor(v, 16);
                    v += __shfl_xor(v, 32);
                    sim[dx][p] = v;
                }
            if (cp == 0) {
                #pragma unroll
                for (int dx = 0; dx < 7; ++dx)
                    *(f4*)&simRed[dy * 7 + dx][lw0] = *(const f4*)sim[dx];
            }
        }
    }
    __syncthreads();

    // ---------------- Softmax over k=49 ----------------
    {
        const int w  = t & 31;
        const int kc = t >> 5;    // 0..15; kc<7 active
        float sred[7], e[7];
        if (kc < 7) {
            float lmax = -3.0e38f;
            #pragma unroll
            for (int j = 0; j < 7; ++j) {
                float s = simRed[kc * 7 + j][w];
                sred[j] = s;
                lmax = fmaxf(lmax, s);
            }
            redBuf[kc][w] = lmax;
        }
        __syncthreads();
        if (kc < 7) {
            float m = redBuf[0][w];
            #pragma unroll
            for (int q = 1; q < 7; ++q) m = fmaxf(m, redBuf[q][w]);
            float ps = 0.f;
            #pragma unroll
            for (int j = 0; j < 7; ++j) {
                e[j] = __expf(sred[j] - m);
                ps += e[j];
            }
            psumBuf[kc][w] = ps;
        }
        __syncthreads();
        if (kc < 7) {
            float l = psumBuf[0][w];
            #pragma unroll
            for (int q = 1; q < 7; ++q) l += psumBuf[q][w];
            float rinv = 1.0f / l;
            #pragma unroll
            for (int j = 0; j < 7; ++j)
                attnBuf[kc * 7 + j][w] = e[j] * rinv;
        }
    }
    __syncthreads();

    // ---------------- Phase B: out[c][w] = sum_k attn[k]*x[c,nbr] ----------------
    {
        const int w4 = t & 7;
        const int ci = t >> 3;            // 0..63 -> 4 channels each
        const int lw0 = w4 * 4;
        const int w0g = wbase + lw0;
        const int c0 = ci * 4;
        const bool hasL = (w0g != 0);
        const bool hasR = (w0g != 60);

        float acc[4][4];
        #pragma unroll
        for (int ch = 0; ch < 4; ++ch)
            #pragma unroll
            for (int p = 0; p < 4; ++p) acc[ch][p] = 0.f;

        for (int dy = 0; dy < 7; ++dy) {
            const int row = h + dy - 3;
            if (row < 0 || row >= Hdim) continue;   // block-uniform
            float a[7][4];
            #pragma unroll
            for (int dx = 0; dx < 7; ++dx) {
                f4 v = *(const f4*)&attnBuf[dy * 7 + dx][lw0];
                a[dx][0]=v.x; a[dx][1]=v.y; a[dx][2]=v.z; a[dx][3]=v.w;
            }
            const float* xr = xb + (size_t)c0 * HW + row * Wdim;
            #pragma unroll
            for (int ch = 0; ch < 4; ++ch) {
                float f[12];
                if (hasL) {
                    f4 v = *(const f4*)(xr + w0g - 4);
                    f[0]=v.x; f[1]=v.y; f[2]=v.z; f[3]=v.w;
                } else { f[0]=0.f; f[1]=0.f; f[2]=0.f; f[3]=0.f; }
                {
                    f4 v = *(const f4*)(xr + w0g);
                    f[4]=v.x; f[5]=v.y; f[6]=v.z; f[7]=v.w;
                }
                if (hasR) {
                    f4 v = *(const f4*)(xr + w0g + 4);
                    f[8]=v.x; f[9]=v.y; f[10]=v.z; f[11]=v.w;
                } else { f[8]=0.f; f[9]=0.f; f[10]=0.f; f[11]=0.f; }
                #pragma unroll
                for (int dx = 0; dx < 7; ++dx)
                    #pragma unroll
                    for (int p = 0; p < 4; ++p)
                        acc[ch][p] += a[dx][p] * f[dx + p + 1];
                xr += HW;
            }
        }

        float* ob = out + (size_t)b * (Cdim * HW) + h * Wdim + wbase;
        #pragma unroll
        for (int ch = 0; ch < 4; ++ch)
            *(f4*)(ob + (size_t)(c0 + ch) * HW + lw0) = *(const f4*)acc[ch];
    }
}

extern "C" void kernel_launch(void* const* d_in, const int* in_sizes, int n_in,
                              void* d_out, int out_size, void* d_ws, size_t ws_size,
                              hipStream_t stream)
{
    const float* x = (const float*)d_in[0];
    float* out = (float*)d_out;
    selfattn_kernel<<<dim3(512), 512, 0, stream>>>(x, out);
}

// Round 4
// 55.831 us; speedup vs baseline: 3.7228x; 3.7228x over previous
//
#include <hip/hip_runtime.h>

typedef float f4 __attribute__((ext_vector_type(4)));

#define Hdim 64
#define Wdim 64
#define Cdim 256
#define HW (Hdim * Wdim)

// Round-2 structure (88 VGPR, no spills) + XCD-locality block decode.
// 256 blocks, 1 per CU. HW round-robin assumption: XCD = bid % 8.
// Decode gives XCD k one (batch, 32-row band): 38 rows x 64KB = 2.4MB < 4MB L2.
__global__ __launch_bounds__(512) void selfattn_kernel(const float* __restrict__ x,
                                                       float* __restrict__ out)
{
    const int bid = blockIdx.x;
    const int k   = bid & 7;
    const int j   = bid >> 3;          // 0..31
    const int b   = k >> 1;            // batch
    const int h   = (k & 1) * 32 + j;  // row within band
    const int t = threadIdx.x;  // 0..511

    __shared__ float simRed[49][64];   // reduced sim
    __shared__ float attnBuf[49][64];  // softmax weights
    __shared__ float redBuf[7][64];    // per-kchunk max
    __shared__ float psumBuf[7][64];   // per-kchunk expsum

    const float* xb = x + (size_t)b * (Cdim * HW);

    // ---------------- Phase A: sim[k][w] ----------------
    // f[j] holds row position (w0 - 4 + j); loads from w0-4, w0, w0+4.
    {
        const int w4 = t & 15;       // w-group
        const int g  = t >> 4;       // 0..31
        const int cp = g & 3;        // channel partition (lane bits 4..5)
        const int dy = g >> 2;       // wave-uniform; dy==7 -> idle wave
        const int w0 = w4 * 4;

        if (dy < 7) {
            float sim[7][4];
            #pragma unroll
            for (int i = 0; i < 7; ++i)
                #pragma unroll
                for (int p = 0; p < 4; ++p) sim[i][p] = 0.f;

            const int row = h + dy - 3;
            if (row >= 0 && row < Hdim) {
                const float* xr = xb + row * Wdim + cp * HW;
                const float* xc = xb + h   * Wdim + cp * HW;
                for (int i = 0; i < 64; ++i) {
                    float f[12];
                    if (w4 > 0) {
                        f4 v = *(const f4*)(xr + w0 - 4);
                        f[0]=v.x; f[1]=v.y; f[2]=v.z; f[3]=v.w;
                    } else {
                        f[0]=0.f; f[1]=0.f; f[2]=0.f; f[3]=0.f;
                    }
                    {
                        f4 v = *(const f4*)(xr + w0);
                        f[4]=v.x; f[5]=v.y; f[6]=v.z; f[7]=v.w;
                    }
                    if (w4 < 15) {
                        f4 v = *(const f4*)(xr + w0 + 4);
                        f[8]=v.x; f[9]=v.y; f[10]=v.z; f[11]=v.w;
                    } else {
                        f[8]=0.f; f[9]=0.f; f[10]=0.f; f[11]=0.f;
                    }
                    f4 cen = *(const f4*)(xc + w0);
                    #pragma unroll
                    for (int dx = 0; dx < 7; ++dx)
                        #pragma unroll
                        for (int p = 0; p < 4; ++p)
                            sim[dx][p] += cen[p] * f[dx + p + 1];
                    xr += 4 * HW;
                    xc += 4 * HW;
                }
            }
            // reduce over the 4 channel partitions (lane bits 4..5)
            #pragma unroll
            for (int dx = 0; dx < 7; ++dx)
                #pragma unroll
                for (int p = 0; p < 4; ++p) {
                    float v = sim[dx][p];
                    v += __shfl_xor(v, 16);
                    v += __shfl_xor(v, 32);
                    sim[dx][p] = v;
                }
            if (cp == 0) {
                #pragma unroll
                for (int dx = 0; dx < 7; ++dx)
                    *(f4*)&simRed[dy * 7 + dx][w0] = *(const f4*)sim[dx];
            }
        }
    }
    __syncthreads();

    // ---------------- Softmax over k=49 ----------------
    {
        const int w  = t & 63;
        const int kc = t >> 6;   // 0..7 ; kc==7 idle
        float sred[7], e[7];
        if (kc < 7) {
            float lmax = -3.0e38f;
            #pragma unroll
            for (int jj = 0; jj < 7; ++jj) {
                float s = simRed[kc * 7 + jj][w];
                sred[jj] = s;
                lmax = fmaxf(lmax, s);
            }
            redBuf[kc][w] = lmax;
        }
        __syncthreads();
        if (kc < 7) {
            float m = redBuf[0][w];
            #pragma unroll
            for (int q = 1; q < 7; ++q) m = fmaxf(m, redBuf[q][w]);
            float ps = 0.f;
            #pragma unroll
            for (int jj = 0; jj < 7; ++jj) {
                e[jj] = __expf(sred[jj] - m);
                ps += e[jj];
            }
            psumBuf[kc][w] = ps;
        }
        __syncthreads();
        if (kc < 7) {
            float l = psumBuf[0][w];
            #pragma unroll
            for (int q = 1; q < 7; ++q) l += psumBuf[q][w];
            float rinv = 1.0f / l;
            #pragma unroll
            for (int jj = 0; jj < 7; ++jj)
                attnBuf[kc * 7 + jj][w] = e[jj] * rinv;
        }
    }
    __syncthreads();

    // ---------------- Phase B: out[c][w] = sum_k attn[k]*x[c,nbr] ----------------
    {
        const int w4 = t & 15;
        const int ci = t >> 4;      // 0..31 -> 8 channels each
        const int w0 = w4 * 4;
        const int c0 = ci * 8;

        float acc[8][4];
        #pragma unroll
        for (int ch = 0; ch < 8; ++ch)
            #pragma unroll
            for (int p = 0; p < 4; ++p) acc[ch][p] = 0.f;

        for (int dy = 0; dy < 7; ++dy) {
            const int row = h + dy - 3;
            if (row < 0 || row >= Hdim) continue;   // block-uniform branch
            float a[7][4];
            #pragma unroll
            for (int dx = 0; dx < 7; ++dx) {
                f4 v = *(const f4*)&attnBuf[dy * 7 + dx][w0];
                a[dx][0]=v.x; a[dx][1]=v.y; a[dx][2]=v.z; a[dx][3]=v.w;
            }
            const float* xr = xb + c0 * HW + row * Wdim;
            #pragma unroll
            for (int ch = 0; ch < 8; ++ch) {
                float f[12];
                if (w4 > 0) {
                    f4 v = *(const f4*)(xr + w0 - 4);
                    f[0]=v.x; f[1]=v.y; f[2]=v.z; f[3]=v.w;
                } else {
                    f[0]=0.f; f[1]=0.f; f[2]=0.f; f[3]=0.f;
                }
                {
                    f4 v = *(const f4*)(xr + w0);
                    f[4]=v.x; f[5]=v.y; f[6]=v.z; f[7]=v.w;
                }
                if (w4 < 15) {
                    f4 v = *(const f4*)(xr + w0 + 4);
                    f[8]=v.x; f[9]=v.y; f[10]=v.z; f[11]=v.w;
                } else {
                    f[8]=0.f; f[9]=0.f; f[10]=0.f; f[11]=0.f;
                }
                #pragma unroll
                for (int dx = 0; dx < 7; ++dx)
                    #pragma unroll
                    for (int p = 0; p < 4; ++p)
                        acc[ch][p] += a[dx][p] * f[dx + p + 1];
                xr += HW;
            }
        }

        float* ob = out + (size_t)b * (Cdim * HW) + h * Wdim;
        #pragma unroll
        for (int ch = 0; ch < 8; ++ch)
            *(f4*)(ob + (c0 + ch) * HW + w0) = *(const f4*)acc[ch];
    }
}

extern "C" void kernel_launch(void* const* d_in, const int* in_sizes, int n_in,
                              void* d_out, int out_size, void* d_ws, size_t ws_size,
                              hipStream_t stream)
{
    const float* x = (const float*)d_in[0];
    float* out = (float*)d_out;
    selfattn_kernel<<<dim3(256), 512, 0, stream>>>(x, out);
}

// Round 5
// 40.308 us; speedup vs baseline: 5.1565x; 1.3851x over previous
//
#include <hip/hip_runtime.h>

typedef float f4 __attribute__((ext_vector_type(4)));

#define Hdim 64
#define Wdim 64
#define Cdim 256
#define HW (Hdim * Wdim)

// Round-4 structure + w-split for occupancy: 512 blocks x 512 threads,
// 2 blocks/CU -> 4 waves/SIMD (was 2). Same XCD-locality decode:
// xcd = bid&7 owns (batch, 32-row h-band), both w-halves on same XCD;
// working set 38 rows x 64KB = 2.4MB < 4MB per-XCD L2.
__global__ __launch_bounds__(512, 4) void selfattn_kernel(const float* __restrict__ x,
                                                          float* __restrict__ out)
{
    const int bid = blockIdx.x;
    const int k   = bid & 7;
    const int seq = bid >> 3;            // 0..63
    const int b   = k >> 1;              // batch
    const int h   = (k & 1) * 32 + (seq >> 1);
    const int wbase = (seq & 1) * 32;    // w-half
    const int t = threadIdx.x;           // 0..511

    __shared__ float simRed[49][32];
    __shared__ float attnBuf[49][32];
    __shared__ float redBuf[7][32];
    __shared__ float psumBuf[7][32];

    const float* xb = x + (size_t)b * (Cdim * HW);

    // ---------------- Phase A: sim[k][w] ----------------
    // thread = (w4: lane bits 0..2, cp: lane bits 3..5, dy: wave).
    // channel for iter i: c = i*8 + cp. f[j] <-> row position (w0g - 4 + j).
    {
        const int w4 = t & 7;            // w-group of 4 (32 wide)
        const int cp = (t >> 3) & 7;     // channel partition
        const int dy = t >> 6;           // wave-uniform; dy==7 idle
        const int lw0 = w4 * 4;
        const int w0g = wbase + lw0;

        if (dy < 7) {
            float sim[7][4];
            #pragma unroll
            for (int dx = 0; dx < 7; ++dx)
                #pragma unroll
                for (int p = 0; p < 4; ++p) sim[dx][p] = 0.f;

            const int row = h + dy - 3;
            if (row >= 0 && row < Hdim) {
                const bool hasL = (w0g != 0);
                const bool hasR = (w0g != 60);
                const float* xr = xb + (size_t)cp * HW + row * Wdim;
                const float* xc = xb + (size_t)cp * HW + h   * Wdim;
                for (int i = 0; i < 32; ++i) {
                    float f[12];
                    if (hasL) {
                        f4 v = *(const f4*)(xr + w0g - 4);
                        f[0]=v.x; f[1]=v.y; f[2]=v.z; f[3]=v.w;
                    } else { f[0]=0.f; f[1]=0.f; f[2]=0.f; f[3]=0.f; }
                    {
                        f4 v = *(const f4*)(xr + w0g);
                        f[4]=v.x; f[5]=v.y; f[6]=v.z; f[7]=v.w;
                    }
                    if (hasR) {
                        f4 v = *(const f4*)(xr + w0g + 4);
                        f[8]=v.x; f[9]=v.y; f[10]=v.z; f[11]=v.w;
                    } else { f[8]=0.f; f[9]=0.f; f[10]=0.f; f[11]=0.f; }
                    f4 cen = *(const f4*)(xc + w0g);
                    #pragma unroll
                    for (int dx = 0; dx < 7; ++dx)
                        #pragma unroll
                        for (int p = 0; p < 4; ++p)
                            sim[dx][p] += cen[p] * f[dx + p + 1];
                    xr += 8 * HW;
                    xc += 8 * HW;
                }
            }
            // reduce over 8 channel partitions (lane bits 3..5)
            #pragma unroll
            for (int dx = 0; dx < 7; ++dx)
                #pragma unroll
                for (int p = 0; p < 4; ++p) {
                    float v = sim[dx][p];
                    v += __shfl_xor(v, 8);
                    v += __shfl_xor(v, 16);
                    v += __shfl_xor(v, 32);
                    sim[dx][p] = v;
                }
            if (cp == 0) {
                #pragma unroll
                for (int dx = 0; dx < 7; ++dx)
                    *(f4*)&simRed[dy * 7 + dx][lw0] = *(const f4*)sim[dx];
            }
        }
    }
    __syncthreads();

    // ---------------- Softmax over k=49 ----------------
    {
        const int w  = t & 31;
        const int kc = t >> 5;    // 0..15; kc<7 active
        float sred[7], e[7];
        if (kc < 7) {
            float lmax = -3.0e38f;
            #pragma unroll
            for (int jj = 0; jj < 7; ++jj) {
                float s = simRed[kc * 7 + jj][w];
                sred[jj] = s;
                lmax = fmaxf(lmax, s);
            }
            redBuf[kc][w] = lmax;
        }
        __syncthreads();
        if (kc < 7) {
            float m = redBuf[0][w];
            #pragma unroll
            for (int q = 1; q < 7; ++q) m = fmaxf(m, redBuf[q][w]);
            float ps = 0.f;
            #pragma unroll
            for (int jj = 0; jj < 7; ++jj) {
                e[jj] = __expf(sred[jj] - m);
                ps += e[jj];
            }
            psumBuf[kc][w] = ps;
        }
        __syncthreads();
        if (kc < 7) {
            float l = psumBuf[0][w];
            #pragma unroll
            for (int q = 1; q < 7; ++q) l += psumBuf[q][w];
            float rinv = 1.0f / l;
            #pragma unroll
            for (int jj = 0; jj < 7; ++jj)
                attnBuf[kc * 7 + jj][w] = e[jj] * rinv;
        }
    }
    __syncthreads();

    // ---------------- Phase B: out[c][w] = sum_k attn[k]*x[c,nbr] ----------------
    {
        const int w4 = t & 7;
        const int ci = t >> 3;           // 0..63 -> 4 channels each
        const int lw0 = w4 * 4;
        const int w0g = wbase + lw0;
        const int c0 = ci * 4;
        const bool hasL = (w0g != 0);
        const bool hasR = (w0g != 60);

        float acc[4][4];
        #pragma unroll
        for (int ch = 0; ch < 4; ++ch)
            #pragma unroll
            for (int p = 0; p < 4; ++p) acc[ch][p] = 0.f;

        for (int dy = 0; dy < 7; ++dy) {
            const int row = h + dy - 3;
            if (row < 0 || row >= Hdim) continue;   // block-uniform
            float a[7][4];
            #pragma unroll
            for (int dx = 0; dx < 7; ++dx) {
                f4 v = *(const f4*)&attnBuf[dy * 7 + dx][lw0];
                a[dx][0]=v.x; a[dx][1]=v.y; a[dx][2]=v.z; a[dx][3]=v.w;
            }
            const float* xr = xb + (size_t)c0 * HW + row * Wdim;
            #pragma unroll
            for (int ch = 0; ch < 4; ++ch) {
                float f[12];
                if (hasL) {
                    f4 v = *(const f4*)(xr + w0g - 4);
                    f[0]=v.x; f[1]=v.y; f[2]=v.z; f[3]=v.w;
                } else { f[0]=0.f; f[1]=0.f; f[2]=0.f; f[3]=0.f; }
                {
                    f4 v = *(const f4*)(xr + w0g);
                    f[4]=v.x; f[5]=v.y; f[6]=v.z; f[7]=v.w;
                }
                if (hasR) {
                    f4 v = *(const f4*)(xr + w0g + 4);
                    f[8]=v.x; f[9]=v.y; f[10]=v.z; f[11]=v.w;
                } else { f[8]=0.f; f[9]=0.f; f[10]=0.f; f[11]=0.f; }
                #pragma unroll
                for (int dx = 0; dx < 7; ++dx)
                    #pragma unroll
                    for (int p = 0; p < 4; ++p)
                        acc[ch][p] += a[dx][p] * f[dx + p + 1];
                xr += HW;
            }
        }

        float* ob = out + (size_t)b * (Cdim * HW) + h * Wdim + wbase;
        #pragma unroll
        for (int ch = 0; ch < 4; ++ch)
            *(f4*)(ob + (size_t)(c0 + ch) * HW + lw0) = *(const f4*)acc[ch];
    }
}

extern "C" void kernel_launch(void* const* d_in, const int* in_sizes, int n_in,
                              void* d_out, int out_size, void* d_ws, size_t ws_size,
                              hipStream_t stream)
{
    const float* x = (const float*)d_in[0];
    float* out = (float*)d_out;
    selfattn_kernel<<<dim3(512), 512, 0, stream>>>(x, out);
}